// Round 16
// baseline (548.014 us; speedup 1.0000x reference)
//
#include <hip/hip_runtime.h>

#define HW 64
#define BATCH 64
#define DDIM 64
#define NSLOT 7
#define NPOS 4096   // 64*64

typedef __attribute__((ext_vector_type(8))) short short8;
typedef __attribute__((ext_vector_type(4))) short short4v;
typedef __attribute__((ext_vector_type(4))) float floatx4;

__device__ __forceinline__ float wave_sum(float x) {
  #pragma unroll
  for (int o = 32; o >= 1; o >>= 1) x += __shfl_xor(x, o, 64);
  return x;
}

__device__ __forceinline__ unsigned short f2bf(float f) {
  unsigned int u = __float_as_uint(f);
  return (unsigned short)((u + 0x7fffu + ((u >> 16) & 1u)) >> 16);
}
__device__ __forceinline__ float bf2f(unsigned short u) {
  return __uint_as_float(((unsigned int)u) << 16);
}
__device__ __forceinline__ short4v pack4(float a, float b, float c, float d) {
  short4v s;
  s.x = (short)f2bf(a); s.y = (short)f2bf(b);
  s.z = (short)f2bf(c); s.w = (short)f2bf(d);
  return s;
}

// ---------------------------------------------------------------------------
// Conv weight prep: fp32 [oc][cin][5][5] -> bf16 fragment order
// [L][tap][ks][mt][lane][j]  (oc = mt*16+(l&15); cin = (ks*4+(l>>4))*8+j)
// ---------------------------------------------------------------------------
__global__ __launch_bounds__(256) void prep_w(
    const float* __restrict__ w1, const float* __restrict__ w2,
    const float* __restrict__ w3, unsigned short* __restrict__ wp)
{
  int idx = blockIdx.x * 256 + threadIdx.x;
  if (idx >= 3 * 102400) return;
  int L = idx / 102400;
  int rem = idx - L * 102400;
  int tap = rem >> 12;
  int r2  = rem & 4095;
  int ks = r2 >> 11;
  int mt = (r2 >> 9) & 3;
  int l  = (r2 >> 3) & 63;
  int j  = r2 & 7;
  int oc  = mt * 16 + (l & 15);
  int cin = (ks * 4 + (l >> 4)) * 8 + j;
  const float* w = (L == 0) ? w1 : (L == 1) ? w2 : w3;
  wp[idx] = f2bf(w[(oc * 64 + cin) * 25 + tap]);
}

// fc1/fc2/k/v weights -> bf16 fragment order [mat][ks][mt][lane][j]
__global__ __launch_bounds__(256) void prep_fcw(
    const float* __restrict__ f1, const float* __restrict__ f2,
    const float* __restrict__ kw, const float* __restrict__ vw,
    unsigned short* __restrict__ dst)
{
  int idx = blockIdx.x * 256 + threadIdx.x;   // 4*4096
  int mat = idx >> 12;
  int r = idx & 4095;
  int ks = r >> 11;
  int mt = (r >> 9) & 3;
  int l  = (r >> 3) & 63;
  int j  = r & 7;
  int oc = mt * 16 + (l & 15);
  int in = (ks * 4 + (l >> 4)) * 8 + j;
  const float* src = (mat == 0) ? f1 : (mat == 1) ? f2 : (mat == 2) ? kw : vw;
  dst[idx] = f2bf(src[oc * 64 + in]);
}

__global__ void prep_s1(const float* __restrict__ f1, float* __restrict__ s1)
{
  int oc = threadIdx.x;  // 64
  float s = 0.f;
  for (int k = 0; k < 64; k++) s += f1[oc * 64 + k];
  s1[oc] = s;
}

// ---------------------------------------------------------------------------
// Conv0: 3-cin fp32 VALU conv + ReLU, writes bf16 NHWC.
// ---------------------------------------------------------------------------
__global__ __launch_bounds__(256) void conv0_relu(
    const float* __restrict__ in, const float* __restrict__ wgt,
    const float* __restrict__ bias, unsigned short* __restrict__ out)
{
  constexpr int TH = 8, TW = 32, OCT = 16, CIN = 3;
  __shared__ __align__(16) float sIn[CIN][TH + 4][40];
  __shared__ __align__(16) float sW[CIN][25][OCT];

  const int bx = blockIdx.x;
  const int tx = bx & 1;
  const int ty = (bx >> 1) & 7;
  const int b  = bx >> 4;
  const int ocb = blockIdx.y * OCT;
  const int x0 = tx * TW, y0 = ty * TH;
  const int tid = threadIdx.x;

  const int sq  = tid & 63;
  const int ocq = tid >> 6;
  const int yy  = sq >> 3;
  const int xx4 = (sq & 7) << 2;
  const int oc0 = ocq << 2;

  float acc[4][4];
  #pragma unroll
  for (int o = 0; o < 4; o++)
    #pragma unroll
    for (int x = 0; x < 4; x++) acc[o][x] = 0.f;

  for (int idx = tid; idx < CIN * 12 * 36; idx += 256) {
    int c  = idx % 36;
    int r  = (idx / 36) % 12;
    int ci = idx / (36 * 12);
    int gy = y0 - 2 + r, gx = x0 - 2 + c;
    float v = 0.f;
    if (gy >= 0 && gy < HW && gx >= 0 && gx < HW)
      v = in[((b * CIN + ci) * HW + gy) * HW + gx];
    sIn[ci][r][c] = v;
  }
  for (int idx = tid; idx < CIN * 25 * OCT; idx += 256) {
    int oc  = idx & 15;
    int tap = (idx >> 4) % 25;
    int ci  = idx / (16 * 25);
    sW[ci][tap][oc] = wgt[((ocb + oc) * CIN + ci) * 25 + tap];
  }
  __syncthreads();

  for (int ci = 0; ci < CIN; ci++) {
    #pragma unroll
    for (int dy = 0; dy < 5; dy++) {
      const float* rp = &sIn[ci][yy + dy][xx4];
      float4 a0 = *(const float4*)rp;
      float4 a1 = *(const float4*)(rp + 4);
      float vals[8] = {a0.x, a0.y, a0.z, a0.w, a1.x, a1.y, a1.z, a1.w};
      #pragma unroll
      for (int dx = 0; dx < 5; dx++) {
        float4 wv = *(const float4*)&sW[ci][dy * 5 + dx][oc0];
        float wa[4] = {wv.x, wv.y, wv.z, wv.w};
        #pragma unroll
        for (int o = 0; o < 4; o++)
          #pragma unroll
          for (int x = 0; x < 4; x++)
            acc[o][x] += wa[o] * vals[dx + x];
      }
    }
  }

  float bb[4];
  #pragma unroll
  for (int o = 0; o < 4; o++) bb[o] = bias[ocb + oc0 + o];
  #pragma unroll
  for (int x = 0; x < 4; x++) {
    int pos = (b << 12) + (y0 + yy) * 64 + (x0 + xx4 + x);
    *(short4v*)&out[pos * 64 + ocb + oc0] =
        pack4(fmaxf(acc[0][x] + bb[0], 0.f), fmaxf(acc[1][x] + bb[1], 0.f),
              fmaxf(acc[2][x] + bb[2], 0.f), fmaxf(acc[3][x] + bb[3], 0.f));
  }
}

// ---------------------------------------------------------------------------
// MFMA conv 5x5, v9: v4's exact LDS layout & pipeline, but 512-thread blocks
// (8 waves x 2 rows; acc[2][4] = 32 VGPRs) -> 16 waves/CU at 2 blocks/CU.
// ---------------------------------------------------------------------------
template<int FUSE_POS>
__global__ __launch_bounds__(512) void conv_mfma(
    const unsigned short* __restrict__ in, const unsigned short* __restrict__ wp,
    const float* __restrict__ bias, unsigned short* __restrict__ out,
    const float* __restrict__ pos_w, const float* __restrict__ pos_b,
    float* __restrict__ stats)
{
  extern __shared__ short lds[];          // 25600 + 2*4096 shorts = 67584 B
  short* sIn = lds;
  uint4* sWu0 = (uint4*)(lds + 25600);    // 512 uint4 = 8 KB (even taps)
  uint4* sWu1 = sWu0 + 512;               // 8 KB (odd taps)

  const int tid = threadIdx.x;
  const int b   = blockIdx.x >> 4;
  const int tile = blockIdx.x & 15;
  const int y0 = (tile >> 2) * 16, x0 = (tile & 3) * 16;

  const uint4* in4 = (const uint4*)in;
  for (int idx = tid; idx < 3200; idx += 512) {
    int p = idx >> 3, c = idx & 7;
    int py = p / 20, px = p - py * 20;
    int gy = y0 - 2 + py, gx = x0 - 2 + px;
    uint4 v = {0u, 0u, 0u, 0u};
    if ((unsigned)gy < 64u && (unsigned)gx < 64u)
      v = in4[(((b << 12) + (gy << 6) + gx) << 3) + c];
    *(uint4*)&sIn[(p << 6) + ((c ^ (p & 7)) << 3)] = v;
  }
  const uint4* wg = (const uint4*)wp;
  sWu0[tid] = wg[tid];                 // 512 threads cover the full tap
  uint4 r0 = wg[512 + tid];            // prefetch tap 1
  __syncthreads();

  const int w  = tid >> 6;             // 8 waves
  const int l  = tid & 63;
  const int lx = l & 15;
  const int kq = l >> 4;
  const int w2 = w * 2;                // 2 rows per wave

  floatx4 zero4 = {0.f, 0.f, 0.f, 0.f};
  floatx4 acc[2][4];   // [yy][mt]
  #pragma unroll
  for (int yy = 0; yy < 2; yy++)
    #pragma unroll
    for (int mt = 0; mt < 4; mt++) acc[yy][mt] = zero4;

  int dy = 0, dx = 0;
  #pragma unroll 1
  for (int t = 0; t < 25; ++t) {
    uint4* cur = (t & 1) ? sWu1 : sWu0;
    if (t < 24) {            // write tap t+1 (loaded last iter) to alt buffer
      uint4* alt = (t & 1) ? sWu0 : sWu1;
      alt[tid] = r0;
    }
    if (t < 23)              // issue load for tap t+2 (drains at end barrier)
      r0 = wg[(t + 2) * 512 + tid];
    const int ix = lx + dx;
    #pragma unroll
    for (int ks = 0; ks < 2; ++ks) {
      const int kc = ks * 4 + kq;
      short8 Bf[2];
      #pragma unroll
      for (int yy = 0; yy < 2; ++yy) {
        int p = (w2 + yy + dy) * 20 + ix;
        Bf[yy] = *(const short8*)&sIn[(p << 6) + ((kc ^ (p & 7)) << 3)];
      }
      #pragma unroll
      for (int mt = 0; mt < 4; ++mt) {
        uint4 Af4 = cur[(ks * 4 + mt) * 64 + l];
        #pragma unroll
        for (int yy = 0; yy < 2; ++yy)
          acc[yy][mt] = __builtin_amdgcn_mfma_f32_16x16x32_bf16(
              *(const short8*)&Af4, Bf[yy], acc[yy][mt], 0, 0, 0);
      }
    }
    if (t < 24) __syncthreads();
    if (++dx == 5) { dx = 0; ++dy; }
  }

  // epilogue
  float4 bv[4];
  #pragma unroll
  for (int mt = 0; mt < 4; ++mt) bv[mt] = *(const float4*)&bias[mt * 16 + kq * 4];

  float4 pw[4][4];  float pb[4][4];
  if (FUSE_POS) {
    #pragma unroll
    for (int mt = 0; mt < 4; ++mt)
      #pragma unroll
      for (int r = 0; r < 4; ++r) {
        int d = mt * 16 + kq * 4 + r;
        pw[mt][r] = *(const float4*)&pos_w[d * 4];
        pb[mt][r] = pos_b[d];
      }
  }

  const int x = x0 + lx;
  const float cx = x * (1.0f / 63.0f);
  float lsum = 0.f, lsq = 0.f;

  #pragma unroll
  for (int yy = 0; yy < 2; ++yy) {
    const int y = y0 + w2 + yy;
    const float ry = y * (1.0f / 63.0f);
    const int base = ((b << 12) + y * 64 + x) * 64;
    #pragma unroll
    for (int mt = 0; mt < 4; ++mt) {
      float v[4];
      #pragma unroll
      for (int r = 0; r < 4; ++r) {
        float f = fmaxf(acc[yy][mt][r] + bv[mt][r], 0.f);
        if (FUSE_POS) {
          f += ry * pw[mt][r].x + cx * pw[mt][r].y + (1.f - ry) * pw[mt][r].z +
               (1.f - cx) * pw[mt][r].w + pb[mt][r];
          lsum += f; lsq += f * f;
        }
        v[r] = f;
      }
      *(short4v*)&out[base + mt * 16 + kq * 4] = pack4(v[0], v[1], v[2], v[3]);
    }
  }

  if (FUSE_POS) {
    lsum = wave_sum(lsum);
    lsq  = wave_sum(lsq);
    if (l == 0) {
      atomicAdd(&stats[b * 2], lsum);
      atomicAdd(&stats[b * 2 + 1], lsq);
    }
  }
}

__global__ void finalize_stats(const float* __restrict__ stats, float* __restrict__ ms)
{
  int b = threadIdx.x;  // 64
  float s = stats[b * 2], q = stats[b * 2 + 1];
  float mean = s * (1.0f / 262144.f);
  float var  = q * (1.0f / 262144.f) - mean * mean;
  ms[b * 2] = mean;
  ms[b * 2 + 1] = rsqrtf(var + 1e-5f);
}

// ---------------------------------------------------------------------------
// Fused MFMA fc chain: batchLN -> fc1(relu) -> fc2 -> LN -> k (bf16 [B,N,D])
// and v stored TRANSPOSED as vT (bf16 [B,D,N]) for the MFMA PV stage.
// ---------------------------------------------------------------------------
__global__ __launch_bounds__(256) void fc_mfma(
    const unsigned short* __restrict__ xb, const float* __restrict__ ms,
    const unsigned short* __restrict__ wall, const float* __restrict__ fc1_b,
    const float* __restrict__ s1, const float* __restrict__ fc2_b,
    const float* __restrict__ ln_w, const float* __restrict__ ln_b,
    unsigned short* __restrict__ kb, unsigned short* __restrict__ vT)
{
  __shared__ short sA[64 * 64];
  __shared__ uint4 sW[2048];   // 4 mats x 512 uint4 = 32 KB
  const int tid = threadIdx.x;
  const int w = tid >> 6, l = tid & 63, lx = l & 15, kq = l >> 4;
  const int p0 = blockIdx.x * 64;
  const int b  = blockIdx.x >> 6;
  const int posb = (blockIdx.x & 63) * 64;
  const int w16 = w * 16;
  const float mean = ms[b * 2], rstd = ms[b * 2 + 1];
  const float rmu = rstd * mean;

  const uint4* wg = (const uint4*)wall;
  #pragma unroll
  for (int i = 0; i < 8; ++i) sW[i * 256 + tid] = wg[i * 256 + tid];

  {
    const uint4* x4 = (const uint4*)xb;
    int r0 = w16 + (l >> 3), c = l & 7;
    uint4 v0 = x4[((p0 + r0) << 3) + c];
    uint4 v1 = x4[((p0 + r0 + 8) << 3) + c];
    *(uint4*)&sA[(r0 << 6) + ((c ^ (r0 & 7)) << 3)] = v0;
    int r1 = r0 + 8;
    *(uint4*)&sA[(r1 << 6) + ((c ^ (r1 & 7)) << 3)] = v1;
  }
  __syncthreads();

  const int brow = w16 + lx;
  floatx4 zero4 = {0.f, 0.f, 0.f, 0.f};

  #define GEMM64(MATI, ACC)                                                   \
    {                                                                         \
      _Pragma("unroll")                                                       \
      for (int ks = 0; ks < 2; ++ks) {                                        \
        int ch = (ks * 4 + kq) ^ (brow & 7);                                  \
        short8 Bf = *(const short8*)&sA[(brow << 6) + (ch << 3)];             \
        _Pragma("unroll")                                                     \
        for (int mt = 0; mt < 4; ++mt) {                                      \
          uint4 Af = sW[(MATI) * 512 + (ks * 4 + mt) * 64 + l];               \
          ACC[mt] = __builtin_amdgcn_mfma_f32_16x16x32_bf16(                  \
              *(const short8*)&Af, Bf, ACC[mt], 0, 0, 0);                     \
        }                                                                     \
      }                                                                       \
    }

  #define LDSW(MT, SV)                                                        \
    {                                                                         \
      int ch = ((MT) * 2 + (kq >> 1)) ^ (brow & 7);                           \
      *(short4v*)&sA[(brow << 6) + (ch << 3) + ((kq & 1) << 2)] = (SV);       \
    }

  // --- GEMM1: fc1 + folded batch-LN + relu ---
  floatx4 a1[4] = {zero4, zero4, zero4, zero4};
  GEMM64(0, a1);
  #pragma unroll
  for (int mt = 0; mt < 4; ++mt) {
    float4 b1v = *(const float4*)&fc1_b[mt * 16 + kq * 4];
    float4 s1v = *(const float4*)&s1[mt * 16 + kq * 4];
    float v[4];
    v[0] = fmaxf(rstd * a1[mt][0] - rmu * s1v.x + b1v.x, 0.f);
    v[1] = fmaxf(rstd * a1[mt][1] - rmu * s1v.y + b1v.y, 0.f);
    v[2] = fmaxf(rstd * a1[mt][2] - rmu * s1v.z + b1v.z, 0.f);
    v[3] = fmaxf(rstd * a1[mt][3] - rmu * s1v.w + b1v.w, 0.f);
    LDSW(mt, pack4(v[0], v[1], v[2], v[3]));
  }

  // --- GEMM2: fc2 + per-position LN ---
  floatx4 a2[4] = {zero4, zero4, zero4, zero4};
  GEMM64(1, a2);
  float y2[4][4];
  float ps = 0.f, pq = 0.f;
  #pragma unroll
  for (int mt = 0; mt < 4; ++mt) {
    float4 b2v = *(const float4*)&fc2_b[mt * 16 + kq * 4];
    float bb[4] = {b2v.x, b2v.y, b2v.z, b2v.w};
    #pragma unroll
    for (int r = 0; r < 4; ++r) {
      float y = a2[mt][r] + bb[r];
      y2[mt][r] = y;
      ps += y; pq += y * y;
    }
  }
  ps += __shfl_xor(ps, 16, 64);  ps += __shfl_xor(ps, 32, 64);
  pq += __shfl_xor(pq, 16, 64);  pq += __shfl_xor(pq, 32, 64);
  float mu2 = ps * (1.f / 64.f);
  float rs2 = rsqrtf(pq * (1.f / 64.f) - mu2 * mu2 + 1e-3f);
  #pragma unroll
  for (int mt = 0; mt < 4; ++mt) {
    float4 lwv = *(const float4*)&ln_w[mt * 16 + kq * 4];
    float4 lbv = *(const float4*)&ln_b[mt * 16 + kq * 4];
    float v[4];
    v[0] = (y2[mt][0] - mu2) * rs2 * lwv.x + lbv.x;
    v[1] = (y2[mt][1] - mu2) * rs2 * lwv.y + lbv.y;
    v[2] = (y2[mt][2] - mu2) * rs2 * lwv.z + lbv.z;
    v[3] = (y2[mt][3] - mu2) * rs2 * lwv.w + lbv.w;
    LDSW(mt, pack4(v[0], v[1], v[2], v[3]));
  }

  // --- GEMM3: k ---
  floatx4 a3[4] = {zero4, zero4, zero4, zero4};
  GEMM64(2, a3);
  const int gbase = ((p0 + brow) << 6) + kq * 4;
  #pragma unroll
  for (int mt = 0; mt < 4; ++mt)
    *(short4v*)&kb[gbase + mt * 16] = pack4(a3[mt][0], a3[mt][1], a3[mt][2], a3[mt][3]);

  // --- GEMM4: v -> transposed store vT[b][d][pos] ---
  floatx4 a4[4] = {zero4, zero4, zero4, zero4};
  GEMM64(3, a4);
  #pragma unroll
  for (int mt = 0; mt < 4; ++mt)
    #pragma unroll
    for (int r = 0; r < 4; ++r)
      vT[((b << 6) + mt * 16 + kq * 4 + r) * 4096 + posb + brow] = f2bf(a4[mt][r]);

  #undef GEMM64
  #undef LDSW
}

// ---------------------------------------------------------------------------
__global__ __launch_bounds__(256) void slots_init(
    const float* __restrict__ mu, const float* __restrict__ ls,
    const float* __restrict__ noise, float* __restrict__ slots)
{
  int idx = blockIdx.x * 256 + threadIdx.x;
  if (idx < BATCH * NSLOT * DDIM) {
    int d = idx & 63;
    slots[idx] = mu[d] + expf(ls[d]) * noise[idx];
  }
}

// ---------------------------------------------------------------------------
// Fused attention: in-block q (LN + matvec) -> QK-MFMA -> softmax(slots) ->
// PV-MFMA.  Writes PARTIAL U/T slabs.  Block = (b, 256-pos tile jt).
// ---------------------------------------------------------------------------
__global__ __launch_bounds__(256) void attn_fused(
    const float* __restrict__ slots, const float* __restrict__ lnw,
    const float* __restrict__ lnb, const float* __restrict__ q_w,
    const unsigned short* __restrict__ kb, const unsigned short* __restrict__ vT,
    float* __restrict__ Upart, float* __restrict__ Tpart)
{
  __shared__ short sLN[7 * 64];
  __shared__ short sQ[16 * 64];
  __shared__ short sP[4][16 * 72];
  __shared__ float sUr[4][7 * 64];
  __shared__ float sT[4][8];
  const int b  = blockIdx.x >> 4;
  const int jt = blockIdx.x & 15;
  const int tid = threadIdx.x;
  const int w = tid >> 6, l = tid & 63, lx = l & 15, kq = l >> 4;
  floatx4 zero4 = {0.f, 0.f, 0.f, 0.f};

  for (int i = tid; i < 1024; i += 256) sQ[i] = 0;

  for (int s = w; s < 7; s += 4) {
    float v = slots[(b * 7 + s) * 64 + l];
    float m = wave_sum(v) * (1.f / 64.f);
    float dv = v - m;
    float var = wave_sum(dv * dv) * (1.f / 64.f);
    sLN[s * 64 + l] = (short)f2bf(dv * rsqrtf(var + 1e-3f) * lnw[l] + lnb[l]);
  }
  for (int s = w; s < 7; s += 4) {
    float acc = 0.f;
    #pragma unroll
    for (int e = 0; e < 64; e += 4) {
      float4 w4v = *(const float4*)&q_w[l * 64 + e];
      acc += w4v.x * bf2f(sLN[s * 64 + e])     + w4v.y * bf2f(sLN[s * 64 + e + 1])
           + w4v.z * bf2f(sLN[s * 64 + e + 2]) + w4v.w * bf2f(sLN[s * 64 + e + 3]);
    }
    sQ[s * 64 + l] = (short)f2bf(acc);
  }
  __syncthreads();

  uint4 qA[2];
  #pragma unroll
  for (int ks = 0; ks < 2; ++ks)
    qA[ks] = *(const uint4*)&sQ[lx * 64 + (ks * 4 + kq) * 8];

  const uint4* kb4 = (const uint4*)kb;
  const int row0 = kq * 4;
  const int j0 = jt * 256 + w * 64;
  float tacc[4] = {0.f, 0.f, 0.f, 0.f};
  short* sPw = sP[w];

  #pragma unroll
  for (int jh = 0; jh < 4; ++jh) {
    const int j = j0 + jh * 16 + lx;
    floatx4 d4 = zero4;
    #pragma unroll
    for (int ks = 0; ks < 2; ++ks) {
      uint4 kB = kb4[(((b << 12) + j) << 3) + ks * 4 + kq];
      d4 = __builtin_amdgcn_mfma_f32_16x16x32_bf16(
          *(const short8*)&qA[ks], *(const short8*)&kB, d4, 0, 0, 0);
    }
    float e[4];
    float mx = -1e30f;
    #pragma unroll
    for (int r = 0; r < 4; ++r) {
      e[r] = (row0 + r < 7) ? d4[r] * 0.125f : -1e30f;
      mx = fmaxf(mx, e[r]);
    }
    mx = fmaxf(mx, __shfl_xor(mx, 16, 64));
    mx = fmaxf(mx, __shfl_xor(mx, 32, 64));
    float sum = 0.f;
    #pragma unroll
    for (int r = 0; r < 4; ++r) {
      e[r] = (row0 + r < 7) ? __expf(e[r] - mx) : 0.f;
      sum += e[r];
    }
    sum += __shfl_xor(sum, 16, 64);
    sum += __shfl_xor(sum, 32, 64);
    float inv = 1.f / sum;
    #pragma unroll
    for (int r = 0; r < 4; ++r) {
      float p = (row0 + r < 7) ? e[r] * inv + 1e-8f : 0.f;
      tacc[r] += p;
      sPw[(row0 + r) * 72 + jh * 16 + lx] = (short)f2bf(p);
    }
  }

  #pragma unroll
  for (int r = 0; r < 4; ++r) {
    if (row0 + r < 7) {
      float t = tacc[r];
      t += __shfl_xor(t, 1, 64);  t += __shfl_xor(t, 2, 64);
      t += __shfl_xor(t, 4, 64);  t += __shfl_xor(t, 8, 64);
      if (lx == 0) sT[w][row0 + r] = t;
    }
  }
  __syncthreads();

  floatx4 uacc[4] = {zero4, zero4, zero4, zero4};
  #pragma unroll
  for (int nt = 0; nt < 4; ++nt) {
    #pragma unroll
    for (int ks = 0; ks < 2; ++ks) {
      short8 pa = *(const short8*)&sPw[lx * 72 + ks * 32 + kq * 8];
      uint4 vB = *(const uint4*)&vT[((b << 6) + nt * 16 + lx) * 4096 +
                                    j0 + ks * 32 + kq * 8];
      uacc[nt] = __builtin_amdgcn_mfma_f32_16x16x32_bf16(
          pa, *(const short8*)&vB, uacc[nt], 0, 0, 0);
    }
  }

  #pragma unroll
  for (int nt = 0; nt < 4; ++nt)
    #pragma unroll
    for (int r = 0; r < 4; ++r)
      if (row0 + r < 7)
        sUr[w][(row0 + r) * 64 + nt * 16 + lx] = uacc[nt][r];
  __syncthreads();

  const int slab = b * 16 + jt;
  for (int i = tid; i < 448; i += 256)
    Upart[slab * 448 + i] = sUr[0][i] + sUr[1][i] + sUr[2][i] + sUr[3][i];
  if (tid < 7)
    Tpart[slab * 7 + tid] = sT[0][tid] + sT[1][tid] + sT[2][tid] + sT[3][tid];
}

// ---------------------------------------------------------------------------
// GRU cell + residual MLP.  One block (192 threads) per (b,s).
// Sums the 16 U/T partial slabs.
// ---------------------------------------------------------------------------
__global__ __launch_bounds__(192) void gru_mlp(
    const float* __restrict__ Upart, const float* __restrict__ Tpart,
    const float* __restrict__ w_ih, const float* __restrict__ w_hh,
    const float* __restrict__ b_ih, const float* __restrict__ b_hh,
    const float* __restrict__ lnfw, const float* __restrict__ lnfb,
    const float* __restrict__ m1w, const float* __restrict__ m1b,
    const float* __restrict__ m2w, const float* __restrict__ m2b,
    float* __restrict__ slots)
{
  __shared__ float sU[64], sSp[64], sGi[192], sGh[192], sH[64], sLn[64], sHid[128];
  const int bs = blockIdx.x;
  const int b = bs / 7, s = bs - b * 7;
  const int t = threadIdx.x;

  if (t < 64) {
    float u = 0.f, Ts = 0.f;
    #pragma unroll 4
    for (int jt = 0; jt < 16; ++jt) {
      u  += Upart[(b * 16 + jt) * 448 + s * 64 + t];
      Ts += Tpart[(b * 16 + jt) * 7 + s];
    }
    sU[t] = u / Ts;
    sSp[t] = slots[bs * 64 + t];
  }
  __syncthreads();
  {
    float gi = b_ih[t], gh = b_hh[t];
    #pragma unroll
    for (int d = 0; d < 64; d += 4) {
      float4 wi = *(const float4*)&w_ih[t * 64 + d];
      float4 wh = *(const float4*)&w_hh[t * 64 + d];
      gi += wi.x * sU[d] + wi.y * sU[d + 1] + wi.z * sU[d + 2] + wi.w * sU[d + 3];
      gh += wh.x * sSp[d] + wh.y * sSp[d + 1] + wh.z * sSp[d + 2] + wh.w * sSp[d + 3];
    }
    sGi[t] = gi; sGh[t] = gh;
  }
  __syncthreads();
  if (t < 64) {
    float r = 1.f / (1.f + expf(-(sGi[t] + sGh[t])));
    float z = 1.f / (1.f + expf(-(sGi[64 + t] + sGh[64 + t])));
    float n = tanhf(sGi[128 + t] + r * sGh[128 + t]);
    float h = (1.f - z) * n + z * sSp[t];
    sH[t] = h;
    float m = wave_sum(h) * (1.f / 64.f);
    float dv = h - m;
    float var = wave_sum(dv * dv) * (1.f / 64.f);
    sLn[t] = dv * rsqrtf(var + 1e-3f) * lnfw[t] + lnfb[t];
  }
  __syncthreads();
  if (t < 128) {
    float a = m1b[t];
    #pragma unroll
    for (int d = 0; d < 64; d += 4) {
      float4 w = *(const float4*)&m1w[t * 64 + d];
      a += w.x * sLn[d] + w.y * sLn[d + 1] + w.z * sLn[d + 2] + w.w * sLn[d + 3];
    }
    sHid[t] = fmaxf(a, 0.f);
  }
  __syncthreads();
  if (t < 64) {
    float a = m2b[t];
    #pragma unroll
    for (int k = 0; k < 128; k += 4) {
      float4 w = *(const float4*)&m2w[t * 128 + k];
      a += w.x * sHid[k] + w.y * sHid[k + 1] + w.z * sHid[k + 2] + w.w * sHid[k + 3];
    }
    slots[bs * 64 + t] = sH[t] + a;
  }
}

// ---------------------------------------------------------------------------
extern "C" void kernel_launch(void* const* d_in, const int* in_sizes, int n_in,
                              void* d_out, int out_size, void* d_ws, size_t ws_size,
                              hipStream_t stream)
{
  const float* image    = (const float*)d_in[0];
  const float* noise    = (const float*)d_in[1];
  const float* conv0_w  = (const float*)d_in[2];
  const float* conv0_b  = (const float*)d_in[3];
  const float* conv1_w  = (const float*)d_in[4];
  const float* conv1_b  = (const float*)d_in[5];
  const float* conv2_w  = (const float*)d_in[6];
  const float* conv2_b  = (const float*)d_in[7];
  const float* conv3_w  = (const float*)d_in[8];
  const float* conv3_b  = (const float*)d_in[9];
  const float* pos_w    = (const float*)d_in[10];
  const float* pos_b    = (const float*)d_in[11];
  const float* fc1_w    = (const float*)d_in[12];
  const float* fc1_b    = (const float*)d_in[13];
  const float* fc2_w    = (const float*)d_in[14];
  const float* fc2_b    = (const float*)d_in[15];
  const float* slots_mu = (const float*)d_in[16];
  const float* slots_ls = (const float*)d_in[17];
  const float* q_w      = (const float*)d_in[18];
  const float* k_w      = (const float*)d_in[19];
  const float* v_w      = (const float*)d_in[20];
  const float* gru_w_ih = (const float*)d_in[21];
  const float* gru_w_hh = (const float*)d_in[22];
  const float* gru_b_ih = (const float*)d_in[23];
  const float* gru_b_hh = (const float*)d_in[24];
  const float* mlp1_w   = (const float*)d_in[25];
  const float* mlp1_b   = (const float*)d_in[26];
  const float* mlp2_w   = (const float*)d_in[27];
  const float* mlp2_b   = (const float*)d_in[28];
  const float* ln_in_w  = (const float*)d_in[29];
  const float* ln_in_b  = (const float*)d_in[30];
  const float* ln_sl_w  = (const float*)d_in[31];
  const float* ln_sl_b  = (const float*)d_in[32];
  const float* ln_ff_w  = (const float*)d_in[33];
  const float* ln_ff_b  = (const float*)d_in[34];

  float* ws = (float*)d_ws;
  float* R1   = ws;                       // 16777216 floats (67 MB)
  float* R2   = R1 + 16777216;            // 16777216 floats (67 MB)
  float* Pbuf = R2 + 16777216;            // 1835008 floats (weights / partial slabs)
  float* qbuf  = Pbuf + 1835008;          // 28672 (unused)
  float* slots = qbuf + 28672;            // 28672
  float* Ubuf  = slots + 28672;           // 28672 (unused)
  float* Tbuf  = Ubuf + 28672;            // 448 (unused)
  float* stats = Tbuf + 448;              // 128
  float* ms    = stats + 128;             // 128

  unsigned short* Wp  = (unsigned short*)Pbuf;    // conv weights 307200 bf16 (dead by attn)
  unsigned short* wfc = Wp + 307200;              // fc/k/v weights 16384 bf16
  float* s1f = (float*)(wfc + 16384);             // fc1 row sums, 64 fp32
  float* Upart = Pbuf + 262144;                   // 458752 floats (after weights)
  float* Tpart = Upart + 458752;                  // 7168 floats
  unsigned short* Y0 = (unsigned short*)R1;       // conv ping
  unsigned short* Y1 = (unsigned short*)R2;       // conv pong
  unsigned short* xb = (unsigned short*)R2;       // conv3 out = [B,N,D] bf16
  unsigned short* kb = (unsigned short*)R1;       // k bf16 [B,N,D]
  unsigned short* vT = kb + 16777216;             // v transposed [B,D,N] bf16

  prep_w<<<1200, 256, 0, stream>>>(conv1_w, conv2_w, conv3_w, Wp);
  prep_fcw<<<64, 256, 0, stream>>>(fc1_w, fc2_w, k_w, v_w, wfc);
  prep_s1<<<1, 64, 0, stream>>>(fc1_w, s1f);
  hipMemsetAsync(stats, 0, 128 * sizeof(float), stream);

  dim3 cgrid(1024, 4);
  conv0_relu<<<cgrid, 256, 0, stream>>>(image, conv0_w, conv0_b, Y0);
  conv_mfma<0><<<1024, 512, 67584, stream>>>(Y0, Wp,          conv1_b, Y1,
                                             nullptr, nullptr, nullptr);
  conv_mfma<0><<<1024, 512, 67584, stream>>>(Y1, Wp + 102400, conv2_b, Y0,
                                             nullptr, nullptr, nullptr);
  conv_mfma<1><<<1024, 512, 67584, stream>>>(Y0, Wp + 204800, conv3_b, xb,
                                             pos_w, pos_b, stats);
  finalize_stats<<<1, 64, 0, stream>>>(stats, ms);

  fc_mfma<<<4096, 256, 0, stream>>>(xb, ms, wfc, fc1_b, s1f, fc2_b,
                                    ln_in_w, ln_in_b, kb, vT);

  slots_init<<<112, 256, 0, stream>>>(slots_mu, slots_ls, noise, slots);

  for (int it = 0; it < 3; it++) {
    attn_fused<<<1024, 256, 0, stream>>>(slots, ln_sl_w, ln_sl_b, q_w,
                                         kb, vT, Upart, Tpart);
    gru_mlp<<<448, 192, 0, stream>>>(Upart, Tpart, gru_w_ih, gru_w_hh,
                                     gru_b_ih, gru_b_hh, ln_ff_w, ln_ff_b,
                                     mlp1_w, mlp1_b, mlp2_w, mlp2_b, slots);
  }

  hipMemcpyAsync(d_out, slots, 28672 * sizeof(float), hipMemcpyDeviceToDevice, stream);
}

// Round 17
// 498.109 us; speedup vs baseline: 1.1002x; 1.1002x over previous
//
#include <hip/hip_runtime.h>

#define HW 64
#define BATCH 64
#define DDIM 64
#define NSLOT 7
#define NPOS 4096   // 64*64

typedef __attribute__((ext_vector_type(8))) short short8;
typedef __attribute__((ext_vector_type(4))) short short4v;
typedef __attribute__((ext_vector_type(4))) float floatx4;

__device__ __forceinline__ float wave_sum(float x) {
  #pragma unroll
  for (int o = 32; o >= 1; o >>= 1) x += __shfl_xor(x, o, 64);
  return x;
}

__device__ __forceinline__ unsigned short f2bf(float f) {
  unsigned int u = __float_as_uint(f);
  return (unsigned short)((u + 0x7fffu + ((u >> 16) & 1u)) >> 16);
}
__device__ __forceinline__ float bf2f(unsigned short u) {
  return __uint_as_float(((unsigned int)u) << 16);
}
__device__ __forceinline__ short4v pack4(float a, float b, float c, float d) {
  short4v s;
  s.x = (short)f2bf(a); s.y = (short)f2bf(b);
  s.z = (short)f2bf(c); s.w = (short)f2bf(d);
  return s;
}

// ---------------------------------------------------------------------------
// Conv weight prep: fp32 [oc][cin][5][5] -> bf16 fragment order
// [L][tap][ks][mt][lane][j]  (oc = mt*16+(l&15); cin = (ks*4+(l>>4))*8+j)
// ---------------------------------------------------------------------------
__global__ __launch_bounds__(256) void prep_w(
    const float* __restrict__ w1, const float* __restrict__ w2,
    const float* __restrict__ w3, unsigned short* __restrict__ wp)
{
  int idx = blockIdx.x * 256 + threadIdx.x;
  if (idx >= 3 * 102400) return;
  int L = idx / 102400;
  int rem = idx - L * 102400;
  int tap = rem >> 12;
  int r2  = rem & 4095;
  int ks = r2 >> 11;
  int mt = (r2 >> 9) & 3;
  int l  = (r2 >> 3) & 63;
  int j  = r2 & 7;
  int oc  = mt * 16 + (l & 15);
  int cin = (ks * 4 + (l >> 4)) * 8 + j;
  const float* w = (L == 0) ? w1 : (L == 1) ? w2 : w3;
  wp[idx] = f2bf(w[(oc * 64 + cin) * 25 + tap]);
}

// fc1/fc2/k/v weights -> bf16 fragment order [mat][ks][mt][lane][j]
__global__ __launch_bounds__(256) void prep_fcw(
    const float* __restrict__ f1, const float* __restrict__ f2,
    const float* __restrict__ kw, const float* __restrict__ vw,
    unsigned short* __restrict__ dst)
{
  int idx = blockIdx.x * 256 + threadIdx.x;   // 4*4096
  int mat = idx >> 12;
  int r = idx & 4095;
  int ks = r >> 11;
  int mt = (r >> 9) & 3;
  int l  = (r >> 3) & 63;
  int j  = r & 7;
  int oc = mt * 16 + (l & 15);
  int in = (ks * 4 + (l >> 4)) * 8 + j;
  const float* src = (mat == 0) ? f1 : (mat == 1) ? f2 : (mat == 2) ? kw : vw;
  dst[idx] = f2bf(src[oc * 64 + in]);
}

__global__ void prep_s1(const float* __restrict__ f1, float* __restrict__ s1)
{
  int oc = threadIdx.x;  // 64
  float s = 0.f;
  for (int k = 0; k < 64; k++) s += f1[oc * 64 + k];
  s1[oc] = s;
}

// ---------------------------------------------------------------------------
// Conv0: 3-cin fp32 VALU conv + ReLU, writes bf16 NHWC.
// ---------------------------------------------------------------------------
__global__ __launch_bounds__(256) void conv0_relu(
    const float* __restrict__ in, const float* __restrict__ wgt,
    const float* __restrict__ bias, unsigned short* __restrict__ out)
{
  constexpr int TH = 8, TW = 32, OCT = 16, CIN = 3;
  __shared__ __align__(16) float sIn[CIN][TH + 4][40];
  __shared__ __align__(16) float sW[CIN][25][OCT];

  const int bx = blockIdx.x;
  const int tx = bx & 1;
  const int ty = (bx >> 1) & 7;
  const int b  = bx >> 4;
  const int ocb = blockIdx.y * OCT;
  const int x0 = tx * TW, y0 = ty * TH;
  const int tid = threadIdx.x;

  const int sq  = tid & 63;
  const int ocq = tid >> 6;
  const int yy  = sq >> 3;
  const int xx4 = (sq & 7) << 2;
  const int oc0 = ocq << 2;

  float acc[4][4];
  #pragma unroll
  for (int o = 0; o < 4; o++)
    #pragma unroll
    for (int x = 0; x < 4; x++) acc[o][x] = 0.f;

  for (int idx = tid; idx < CIN * 12 * 36; idx += 256) {
    int c  = idx % 36;
    int r  = (idx / 36) % 12;
    int ci = idx / (36 * 12);
    int gy = y0 - 2 + r, gx = x0 - 2 + c;
    float v = 0.f;
    if (gy >= 0 && gy < HW && gx >= 0 && gx < HW)
      v = in[((b * CIN + ci) * HW + gy) * HW + gx];
    sIn[ci][r][c] = v;
  }
  for (int idx = tid; idx < CIN * 25 * OCT; idx += 256) {
    int oc  = idx & 15;
    int tap = (idx >> 4) % 25;
    int ci  = idx / (16 * 25);
    sW[ci][tap][oc] = wgt[((ocb + oc) * CIN + ci) * 25 + tap];
  }
  __syncthreads();

  for (int ci = 0; ci < CIN; ci++) {
    #pragma unroll
    for (int dy = 0; dy < 5; dy++) {
      const float* rp = &sIn[ci][yy + dy][xx4];
      float4 a0 = *(const float4*)rp;
      float4 a1 = *(const float4*)(rp + 4);
      float vals[8] = {a0.x, a0.y, a0.z, a0.w, a1.x, a1.y, a1.z, a1.w};
      #pragma unroll
      for (int dx = 0; dx < 5; dx++) {
        float4 wv = *(const float4*)&sW[ci][dy * 5 + dx][oc0];
        float wa[4] = {wv.x, wv.y, wv.z, wv.w};
        #pragma unroll
        for (int o = 0; o < 4; o++)
          #pragma unroll
          for (int x = 0; x < 4; x++)
            acc[o][x] += wa[o] * vals[dx + x];
      }
    }
  }

  float bb[4];
  #pragma unroll
  for (int o = 0; o < 4; o++) bb[o] = bias[ocb + oc0 + o];
  #pragma unroll
  for (int x = 0; x < 4; x++) {
    int pos = (b << 12) + (y0 + yy) * 64 + (x0 + xx4 + x);
    *(short4v*)&out[pos * 64 + ocb + oc0] =
        pack4(fmaxf(acc[0][x] + bb[0], 0.f), fmaxf(acc[1][x] + bb[1], 0.f),
              fmaxf(acc[2][x] + bb[2], 0.f), fmaxf(acc[3][x] + bb[3], 0.f));
  }
}

// ---------------------------------------------------------------------------
// MFMA conv 5x5, v4 (proven best ~92-100 us): double-buffered 8 KB LDS
// weight buffers, 2-deep global prefetch, one barrier per tap.
// ---------------------------------------------------------------------------
template<int FUSE_POS>
__global__ __launch_bounds__(256) void conv_mfma(
    const unsigned short* __restrict__ in, const unsigned short* __restrict__ wp,
    const float* __restrict__ bias, unsigned short* __restrict__ out,
    const float* __restrict__ pos_w, const float* __restrict__ pos_b,
    float* __restrict__ stats)
{
  extern __shared__ short lds[];          // 25600 + 2*4096 shorts = 67584 B
  short* sIn = lds;
  uint4* sWu0 = (uint4*)(lds + 25600);    // 512 uint4 = 8 KB (even taps)
  uint4* sWu1 = sWu0 + 512;               // 8 KB (odd taps)

  const int tid = threadIdx.x;
  const int b   = blockIdx.x >> 4;
  const int tile = blockIdx.x & 15;
  const int y0 = (tile >> 2) * 16, x0 = (tile & 3) * 16;

  const uint4* in4 = (const uint4*)in;
  for (int idx = tid; idx < 3200; idx += 256) {
    int p = idx >> 3, c = idx & 7;
    int py = p / 20, px = p - py * 20;
    int gy = y0 - 2 + py, gx = x0 - 2 + px;
    uint4 v = {0u, 0u, 0u, 0u};
    if ((unsigned)gy < 64u && (unsigned)gx < 64u)
      v = in4[(((b << 12) + (gy << 6) + gx) << 3) + c];
    *(uint4*)&sIn[(p << 6) + ((c ^ (p & 7)) << 3)] = v;
  }
  const uint4* wg = (const uint4*)wp;
  sWu0[tid] = wg[tid];
  sWu0[256 + tid] = wg[256 + tid];
  uint4 r0 = wg[512 + tid];
  uint4 r1 = wg[512 + 256 + tid];
  __syncthreads();

  const int w  = tid >> 6;
  const int l  = tid & 63;
  const int lx = l & 15;
  const int kq = l >> 4;
  const int w4 = w * 4;

  floatx4 zero4 = {0.f, 0.f, 0.f, 0.f};
  floatx4 acc[4][4];   // [yy][mt]
  #pragma unroll
  for (int yy = 0; yy < 4; yy++)
    #pragma unroll
    for (int mt = 0; mt < 4; mt++) acc[yy][mt] = zero4;

  int dy = 0, dx = 0;
  #pragma unroll 1
  for (int t = 0; t < 25; ++t) {
    uint4* cur = (t & 1) ? sWu1 : sWu0;
    if (t < 24) {            // write tap t+1 (loaded last iter) to alt buffer
      uint4* alt = (t & 1) ? sWu0 : sWu1;
      alt[tid] = r0;
      alt[256 + tid] = r1;
    }
    if (t < 23) {            // issue loads for tap t+2 (drain at end barrier)
      r0 = wg[(t + 2) * 512 + tid];
      r1 = wg[(t + 2) * 512 + 256 + tid];
    }
    const int ix = lx + dx;
    #pragma unroll
    for (int ks = 0; ks < 2; ++ks) {
      const int kc = ks * 4 + kq;
      short8 Bf[4];
      #pragma unroll
      for (int yy = 0; yy < 4; ++yy) {
        int p = (w4 + yy + dy) * 20 + ix;
        Bf[yy] = *(const short8*)&sIn[(p << 6) + ((kc ^ (p & 7)) << 3)];
      }
      #pragma unroll
      for (int mt = 0; mt < 4; ++mt) {
        uint4 Af4 = cur[(ks * 4 + mt) * 64 + l];
        #pragma unroll
        for (int yy = 0; yy < 4; ++yy)
          acc[yy][mt] = __builtin_amdgcn_mfma_f32_16x16x32_bf16(
              *(const short8*)&Af4, Bf[yy], acc[yy][mt], 0, 0, 0);
      }
    }
    if (t < 24) __syncthreads();
    if (++dx == 5) { dx = 0; ++dy; }
  }

  // epilogue
  float4 bv[4];
  #pragma unroll
  for (int mt = 0; mt < 4; ++mt) bv[mt] = *(const float4*)&bias[mt * 16 + kq * 4];

  float4 pw[4][4];  float pb[4][4];
  if (FUSE_POS) {
    #pragma unroll
    for (int mt = 0; mt < 4; ++mt)
      #pragma unroll
      for (int r = 0; r < 4; ++r) {
        int d = mt * 16 + kq * 4 + r;
        pw[mt][r] = *(const float4*)&pos_w[d * 4];
        pb[mt][r] = pos_b[d];
      }
  }

  const int x = x0 + lx;
  const float cx = x * (1.0f / 63.0f);
  float lsum = 0.f, lsq = 0.f;

  #pragma unroll
  for (int yy = 0; yy < 4; ++yy) {
    const int y = y0 + w4 + yy;
    const float ry = y * (1.0f / 63.0f);
    const int base = ((b << 12) + y * 64 + x) * 64;
    #pragma unroll
    for (int mt = 0; mt < 4; ++mt) {
      float v[4];
      #pragma unroll
      for (int r = 0; r < 4; ++r) {
        float f = fmaxf(acc[yy][mt][r] + bv[mt][r], 0.f);
        if (FUSE_POS) {
          f += ry * pw[mt][r].x + cx * pw[mt][r].y + (1.f - ry) * pw[mt][r].z +
               (1.f - cx) * pw[mt][r].w + pb[mt][r];
          lsum += f; lsq += f * f;
        }
        v[r] = f;
      }
      *(short4v*)&out[base + mt * 16 + kq * 4] = pack4(v[0], v[1], v[2], v[3]);
    }
  }

  if (FUSE_POS) {
    lsum = wave_sum(lsum);
    lsq  = wave_sum(lsq);
    if (l == 0) {
      atomicAdd(&stats[b * 2], lsum);
      atomicAdd(&stats[b * 2 + 1], lsq);
    }
  }
}

__global__ void finalize_stats(const float* __restrict__ stats, float* __restrict__ ms)
{
  int b = threadIdx.x;  // 64
  float s = stats[b * 2], q = stats[b * 2 + 1];
  float mean = s * (1.0f / 262144.f);
  float var  = q * (1.0f / 262144.f) - mean * mean;
  ms[b * 2] = mean;
  ms[b * 2 + 1] = rsqrtf(var + 1e-5f);
}

// ---------------------------------------------------------------------------
// Fused MFMA fc chain: batchLN -> fc1(relu) -> fc2 -> LN -> k (bf16 [B,N,D])
// and v stored TRANSPOSED as vT (bf16 [B,D,N]) for the MFMA PV stage.
// ---------------------------------------------------------------------------
__global__ __launch_bounds__(256) void fc_mfma(
    const unsigned short* __restrict__ xb, const float* __restrict__ ms,
    const unsigned short* __restrict__ wall, const float* __restrict__ fc1_b,
    const float* __restrict__ s1, const float* __restrict__ fc2_b,
    const float* __restrict__ ln_w, const float* __restrict__ ln_b,
    unsigned short* __restrict__ kb, unsigned short* __restrict__ vT)
{
  __shared__ short sA[64 * 64];
  __shared__ uint4 sW[2048];   // 4 mats x 512 uint4 = 32 KB
  const int tid = threadIdx.x;
  const int w = tid >> 6, l = tid & 63, lx = l & 15, kq = l >> 4;
  const int p0 = blockIdx.x * 64;
  const int b  = blockIdx.x >> 6;
  const int posb = (blockIdx.x & 63) * 64;
  const int w16 = w * 16;
  const float mean = ms[b * 2], rstd = ms[b * 2 + 1];
  const float rmu = rstd * mean;

  const uint4* wg = (const uint4*)wall;
  #pragma unroll
  for (int i = 0; i < 8; ++i) sW[i * 256 + tid] = wg[i * 256 + tid];

  {
    const uint4* x4 = (const uint4*)xb;
    int r0 = w16 + (l >> 3), c = l & 7;
    uint4 v0 = x4[((p0 + r0) << 3) + c];
    uint4 v1 = x4[((p0 + r0 + 8) << 3) + c];
    *(uint4*)&sA[(r0 << 6) + ((c ^ (r0 & 7)) << 3)] = v0;
    int r1 = r0 + 8;
    *(uint4*)&sA[(r1 << 6) + ((c ^ (r1 & 7)) << 3)] = v1;
  }
  __syncthreads();

  const int brow = w16 + lx;
  floatx4 zero4 = {0.f, 0.f, 0.f, 0.f};

  #define GEMM64(MATI, ACC)                                                   \
    {                                                                         \
      _Pragma("unroll")                                                       \
      for (int ks = 0; ks < 2; ++ks) {                                        \
        int ch = (ks * 4 + kq) ^ (brow & 7);                                  \
        short8 Bf = *(const short8*)&sA[(brow << 6) + (ch << 3)];             \
        _Pragma("unroll")                                                     \
        for (int mt = 0; mt < 4; ++mt) {                                      \
          uint4 Af = sW[(MATI) * 512 + (ks * 4 + mt) * 64 + l];               \
          ACC[mt] = __builtin_amdgcn_mfma_f32_16x16x32_bf16(                  \
              *(const short8*)&Af, Bf, ACC[mt], 0, 0, 0);                     \
        }                                                                     \
      }                                                                       \
    }

  #define LDSW(MT, SV)                                                        \
    {                                                                         \
      int ch = ((MT) * 2 + (kq >> 1)) ^ (brow & 7);                           \
      *(short4v*)&sA[(brow << 6) + (ch << 3) + ((kq & 1) << 2)] = (SV);       \
    }

  // --- GEMM1: fc1 + folded batch-LN + relu ---
  floatx4 a1[4] = {zero4, zero4, zero4, zero4};
  GEMM64(0, a1);
  #pragma unroll
  for (int mt = 0; mt < 4; ++mt) {
    float4 b1v = *(const float4*)&fc1_b[mt * 16 + kq * 4];
    float4 s1v = *(const float4*)&s1[mt * 16 + kq * 4];
    float v[4];
    v[0] = fmaxf(rstd * a1[mt][0] - rmu * s1v.x + b1v.x, 0.f);
    v[1] = fmaxf(rstd * a1[mt][1] - rmu * s1v.y + b1v.y, 0.f);
    v[2] = fmaxf(rstd * a1[mt][2] - rmu * s1v.z + b1v.z, 0.f);
    v[3] = fmaxf(rstd * a1[mt][3] - rmu * s1v.w + b1v.w, 0.f);
    LDSW(mt, pack4(v[0], v[1], v[2], v[3]));
  }

  // --- GEMM2: fc2 + per-position LN ---
  floatx4 a2[4] = {zero4, zero4, zero4, zero4};
  GEMM64(1, a2);
  float y2[4][4];
  float ps = 0.f, pq = 0.f;
  #pragma unroll
  for (int mt = 0; mt < 4; ++mt) {
    float4 b2v = *(const float4*)&fc2_b[mt * 16 + kq * 4];
    float bb[4] = {b2v.x, b2v.y, b2v.z, b2v.w};
    #pragma unroll
    for (int r = 0; r < 4; ++r) {
      float y = a2[mt][r] + bb[r];
      y2[mt][r] = y;
      ps += y; pq += y * y;
    }
  }
  ps += __shfl_xor(ps, 16, 64);  ps += __shfl_xor(ps, 32, 64);
  pq += __shfl_xor(pq, 16, 64);  pq += __shfl_xor(pq, 32, 64);
  float mu2 = ps * (1.f / 64.f);
  float rs2 = rsqrtf(pq * (1.f / 64.f) - mu2 * mu2 + 1e-3f);
  #pragma unroll
  for (int mt = 0; mt < 4; ++mt) {
    float4 lwv = *(const float4*)&ln_w[mt * 16 + kq * 4];
    float4 lbv = *(const float4*)&ln_b[mt * 16 + kq * 4];
    float v[4];
    v[0] = (y2[mt][0] - mu2) * rs2 * lwv.x + lbv.x;
    v[1] = (y2[mt][1] - mu2) * rs2 * lwv.y + lbv.y;
    v[2] = (y2[mt][2] - mu2) * rs2 * lwv.z + lbv.z;
    v[3] = (y2[mt][3] - mu2) * rs2 * lwv.w + lbv.w;
    LDSW(mt, pack4(v[0], v[1], v[2], v[3]));
  }

  // --- GEMM3: k ---
  floatx4 a3[4] = {zero4, zero4, zero4, zero4};
  GEMM64(2, a3);
  const int gbase = ((p0 + brow) << 6) + kq * 4;
  #pragma unroll
  for (int mt = 0; mt < 4; ++mt)
    *(short4v*)&kb[gbase + mt * 16] = pack4(a3[mt][0], a3[mt][1], a3[mt][2], a3[mt][3]);

  // --- GEMM4: v -> transposed store vT[b][d][pos] ---
  floatx4 a4[4] = {zero4, zero4, zero4, zero4};
  GEMM64(3, a4);
  #pragma unroll
  for (int mt = 0; mt < 4; ++mt)
    #pragma unroll
    for (int r = 0; r < 4; ++r)
      vT[((b << 6) + mt * 16 + kq * 4 + r) * 4096 + posb + brow] = f2bf(a4[mt][r]);

  #undef GEMM64
  #undef LDSW
}

// ---------------------------------------------------------------------------
__global__ __launch_bounds__(256) void slots_init(
    const float* __restrict__ mu, const float* __restrict__ ls,
    const float* __restrict__ noise, float* __restrict__ slots)
{
  int idx = blockIdx.x * 256 + threadIdx.x;
  if (idx < BATCH * NSLOT * DDIM) {
    int d = idx & 63;
    slots[idx] = mu[d] + expf(ls[d]) * noise[idx];
  }
}

// ---------------------------------------------------------------------------
// Fused attention: in-block q (LN + matvec) -> QK-MFMA -> softmax(slots) ->
// PV-MFMA.  Writes PARTIAL U/T slabs.  Block = (b, 256-pos tile jt).
// ---------------------------------------------------------------------------
__global__ __launch_bounds__(256) void attn_fused(
    const float* __restrict__ slots, const float* __restrict__ lnw,
    const float* __restrict__ lnb, const float* __restrict__ q_w,
    const unsigned short* __restrict__ kb, const unsigned short* __restrict__ vT,
    float* __restrict__ Upart, float* __restrict__ Tpart)
{
  __shared__ short sLN[7 * 64];
  __shared__ short sQ[16 * 64];
  __shared__ short sP[4][16 * 72];
  __shared__ float sUr[4][7 * 64];
  __shared__ float sT[4][8];
  const int b  = blockIdx.x >> 4;
  const int jt = blockIdx.x & 15;
  const int tid = threadIdx.x;
  const int w = tid >> 6, l = tid & 63, lx = l & 15, kq = l >> 4;
  floatx4 zero4 = {0.f, 0.f, 0.f, 0.f};

  for (int i = tid; i < 1024; i += 256) sQ[i] = 0;

  for (int s = w; s < 7; s += 4) {
    float v = slots[(b * 7 + s) * 64 + l];
    float m = wave_sum(v) * (1.f / 64.f);
    float dv = v - m;
    float var = wave_sum(dv * dv) * (1.f / 64.f);
    sLN[s * 64 + l] = (short)f2bf(dv * rsqrtf(var + 1e-3f) * lnw[l] + lnb[l]);
  }
  for (int s = w; s < 7; s += 4) {
    float acc = 0.f;
    #pragma unroll
    for (int e = 0; e < 64; e += 4) {
      float4 w4v = *(const float4*)&q_w[l * 64 + e];
      acc += w4v.x * bf2f(sLN[s * 64 + e])     + w4v.y * bf2f(sLN[s * 64 + e + 1])
           + w4v.z * bf2f(sLN[s * 64 + e + 2]) + w4v.w * bf2f(sLN[s * 64 + e + 3]);
    }
    sQ[s * 64 + l] = (short)f2bf(acc);
  }
  __syncthreads();

  uint4 qA[2];
  #pragma unroll
  for (int ks = 0; ks < 2; ++ks)
    qA[ks] = *(const uint4*)&sQ[lx * 64 + (ks * 4 + kq) * 8];

  const uint4* kb4 = (const uint4*)kb;
  const int row0 = kq * 4;
  const int j0 = jt * 256 + w * 64;
  float tacc[4] = {0.f, 0.f, 0.f, 0.f};
  short* sPw = sP[w];

  #pragma unroll
  for (int jh = 0; jh < 4; ++jh) {
    const int j = j0 + jh * 16 + lx;
    floatx4 d4 = zero4;
    #pragma unroll
    for (int ks = 0; ks < 2; ++ks) {
      uint4 kB = kb4[(((b << 12) + j) << 3) + ks * 4 + kq];
      d4 = __builtin_amdgcn_mfma_f32_16x16x32_bf16(
          *(const short8*)&qA[ks], *(const short8*)&kB, d4, 0, 0, 0);
    }
    float e[4];
    float mx = -1e30f;
    #pragma unroll
    for (int r = 0; r < 4; ++r) {
      e[r] = (row0 + r < 7) ? d4[r] * 0.125f : -1e30f;
      mx = fmaxf(mx, e[r]);
    }
    mx = fmaxf(mx, __shfl_xor(mx, 16, 64));
    mx = fmaxf(mx, __shfl_xor(mx, 32, 64));
    float sum = 0.f;
    #pragma unroll
    for (int r = 0; r < 4; ++r) {
      e[r] = (row0 + r < 7) ? __expf(e[r] - mx) : 0.f;
      sum += e[r];
    }
    sum += __shfl_xor(sum, 16, 64);
    sum += __shfl_xor(sum, 32, 64);
    float inv = 1.f / sum;
    #pragma unroll
    for (int r = 0; r < 4; ++r) {
      float p = (row0 + r < 7) ? e[r] * inv + 1e-8f : 0.f;
      tacc[r] += p;
      sPw[(row0 + r) * 72 + jh * 16 + lx] = (short)f2bf(p);
    }
  }

  #pragma unroll
  for (int r = 0; r < 4; ++r) {
    if (row0 + r < 7) {
      float t = tacc[r];
      t += __shfl_xor(t, 1, 64);  t += __shfl_xor(t, 2, 64);
      t += __shfl_xor(t, 4, 64);  t += __shfl_xor(t, 8, 64);
      if (lx == 0) sT[w][row0 + r] = t;
    }
  }
  __syncthreads();

  floatx4 uacc[4] = {zero4, zero4, zero4, zero4};
  #pragma unroll
  for (int nt = 0; nt < 4; ++nt) {
    #pragma unroll
    for (int ks = 0; ks < 2; ++ks) {
      short8 pa = *(const short8*)&sPw[lx * 72 + ks * 32 + kq * 8];
      uint4 vB = *(const uint4*)&vT[((b << 6) + nt * 16 + lx) * 4096 +
                                    j0 + ks * 32 + kq * 8];
      uacc[nt] = __builtin_amdgcn_mfma_f32_16x16x32_bf16(
          pa, *(const short8*)&vB, uacc[nt], 0, 0, 0);
    }
  }

  #pragma unroll
  for (int nt = 0; nt < 4; ++nt)
    #pragma unroll
    for (int r = 0; r < 4; ++r)
      if (row0 + r < 7)
        sUr[w][(row0 + r) * 64 + nt * 16 + lx] = uacc[nt][r];
  __syncthreads();

  const int slab = b * 16 + jt;
  for (int i = tid; i < 448; i += 256)
    Upart[slab * 448 + i] = sUr[0][i] + sUr[1][i] + sUr[2][i] + sUr[3][i];
  if (tid < 7)
    Tpart[slab * 7 + tid] = sT[0][tid] + sT[1][tid] + sT[2][tid] + sT[3][tid];
}

// ---------------------------------------------------------------------------
// GRU cell + residual MLP.  One block (192 threads) per (b,s).
// Sums the 16 U/T partial slabs.
// ---------------------------------------------------------------------------
__global__ __launch_bounds__(192) void gru_mlp(
    const float* __restrict__ Upart, const float* __restrict__ Tpart,
    const float* __restrict__ w_ih, const float* __restrict__ w_hh,
    const float* __restrict__ b_ih, const float* __restrict__ b_hh,
    const float* __restrict__ lnfw, const float* __restrict__ lnfb,
    const float* __restrict__ m1w, const float* __restrict__ m1b,
    const float* __restrict__ m2w, const float* __restrict__ m2b,
    float* __restrict__ slots)
{
  __shared__ float sU[64], sSp[64], sGi[192], sGh[192], sH[64], sLn[64], sHid[128];
  const int bs = blockIdx.x;
  const int b = bs / 7, s = bs - b * 7;
  const int t = threadIdx.x;

  if (t < 64) {
    float u = 0.f, Ts = 0.f;
    #pragma unroll 4
    for (int jt = 0; jt < 16; ++jt) {
      u  += Upart[(b * 16 + jt) * 448 + s * 64 + t];
      Ts += Tpart[(b * 16 + jt) * 7 + s];
    }
    sU[t] = u / Ts;
    sSp[t] = slots[bs * 64 + t];
  }
  __syncthreads();
  {
    float gi = b_ih[t], gh = b_hh[t];
    #pragma unroll
    for (int d = 0; d < 64; d += 4) {
      float4 wi = *(const float4*)&w_ih[t * 64 + d];
      float4 wh = *(const float4*)&w_hh[t * 64 + d];
      gi += wi.x * sU[d] + wi.y * sU[d + 1] + wi.z * sU[d + 2] + wi.w * sU[d + 3];
      gh += wh.x * sSp[d] + wh.y * sSp[d + 1] + wh.z * sSp[d + 2] + wh.w * sSp[d + 3];
    }
    sGi[t] = gi; sGh[t] = gh;
  }
  __syncthreads();
  if (t < 64) {
    float r = 1.f / (1.f + expf(-(sGi[t] + sGh[t])));
    float z = 1.f / (1.f + expf(-(sGi[64 + t] + sGh[64 + t])));
    float n = tanhf(sGi[128 + t] + r * sGh[128 + t]);
    float h = (1.f - z) * n + z * sSp[t];
    sH[t] = h;
    float m = wave_sum(h) * (1.f / 64.f);
    float dv = h - m;
    float var = wave_sum(dv * dv) * (1.f / 64.f);
    sLn[t] = dv * rsqrtf(var + 1e-3f) * lnfw[t] + lnfb[t];
  }
  __syncthreads();
  if (t < 128) {
    float a = m1b[t];
    #pragma unroll
    for (int d = 0; d < 64; d += 4) {
      float4 w = *(const float4*)&m1w[t * 64 + d];
      a += w.x * sLn[d] + w.y * sLn[d + 1] + w.z * sLn[d + 2] + w.w * sLn[d + 3];
    }
    sHid[t] = fmaxf(a, 0.f);
  }
  __syncthreads();
  if (t < 64) {
    float a = m2b[t];
    #pragma unroll
    for (int k = 0; k < 128; k += 4) {
      float4 w = *(const float4*)&m2w[t * 128 + k];
      a += w.x * sHid[k] + w.y * sHid[k + 1] + w.z * sHid[k + 2] + w.w * sHid[k + 3];
    }
    slots[bs * 64 + t] = sH[t] + a;
  }
}

// ---------------------------------------------------------------------------
extern "C" void kernel_launch(void* const* d_in, const int* in_sizes, int n_in,
                              void* d_out, int out_size, void* d_ws, size_t ws_size,
                              hipStream_t stream)
{
  const float* image    = (const float*)d_in[0];
  const float* noise    = (const float*)d_in[1];
  const float* conv0_w  = (const float*)d_in[2];
  const float* conv0_b  = (const float*)d_in[3];
  const float* conv1_w  = (const float*)d_in[4];
  const float* conv1_b  = (const float*)d_in[5];
  const float* conv2_w  = (const float*)d_in[6];
  const float* conv2_b  = (const float*)d_in[7];
  const float* conv3_w  = (const float*)d_in[8];
  const float* conv3_b  = (const float*)d_in[9];
  const float* pos_w    = (const float*)d_in[10];
  const float* pos_b    = (const float*)d_in[11];
  const float* fc1_w    = (const float*)d_in[12];
  const float* fc1_b    = (const float*)d_in[13];
  const float* fc2_w    = (const float*)d_in[14];
  const float* fc2_b    = (const float*)d_in[15];
  const float* slots_mu = (const float*)d_in[16];
  const float* slots_ls = (const float*)d_in[17];
  const float* q_w      = (const float*)d_in[18];
  const float* k_w      = (const float*)d_in[19];
  const float* v_w      = (const float*)d_in[20];
  const float* gru_w_ih = (const float*)d_in[21];
  const float* gru_w_hh = (const float*)d_in[22];
  const float* gru_b_ih = (const float*)d_in[23];
  const float* gru_b_hh = (const float*)d_in[24];
  const float* mlp1_w   = (const float*)d_in[25];
  const float* mlp1_b   = (const float*)d_in[26];
  const float* mlp2_w   = (const float*)d_in[27];
  const float* mlp2_b   = (const float*)d_in[28];
  const float* ln_in_w  = (const float*)d_in[29];
  const float* ln_in_b  = (const float*)d_in[30];
  const float* ln_sl_w  = (const float*)d_in[31];
  const float* ln_sl_b  = (const float*)d_in[32];
  const float* ln_ff_w  = (const float*)d_in[33];
  const float* ln_ff_b  = (const float*)d_in[34];

  float* ws = (float*)d_ws;
  float* R1   = ws;                       // 16777216 floats (67 MB)
  float* R2   = R1 + 16777216;            // 16777216 floats (67 MB)
  float* Pbuf = R2 + 16777216;            // 1835008 floats (weights / partial slabs)
  float* qbuf  = Pbuf + 1835008;          // 28672 (unused)
  float* slots = qbuf + 28672;            // 28672
  float* Ubuf  = slots + 28672;           // 28672 (unused)
  float* Tbuf  = Ubuf + 28672;            // 448 (unused)
  float* stats = Tbuf + 448;              // 128
  float* ms    = stats + 128;             // 128

  unsigned short* Wp  = (unsigned short*)Pbuf;    // conv weights 307200 bf16 (dead by attn)
  unsigned short* wfc = Wp + 307200;              // fc/k/v weights 16384 bf16
  float* s1f = (float*)(wfc + 16384);             // fc1 row sums, 64 fp32
  float* Upart = Pbuf + 262144;                   // 458752 floats (after weights)
  float* Tpart = Upart + 458752;                  // 7168 floats
  unsigned short* Y0 = (unsigned short*)R1;       // conv ping
  unsigned short* Y1 = (unsigned short*)R2;       // conv pong
  unsigned short* xb = (unsigned short*)R2;       // conv3 out = [B,N,D] bf16
  unsigned short* kb = (unsigned short*)R1;       // k bf16 [B,N,D]
  unsigned short* vT = kb + 16777216;             // v transposed [B,D,N] bf16

  prep_w<<<1200, 256, 0, stream>>>(conv1_w, conv2_w, conv3_w, Wp);
  prep_fcw<<<64, 256, 0, stream>>>(fc1_w, fc2_w, k_w, v_w, wfc);
  prep_s1<<<1, 64, 0, stream>>>(fc1_w, s1f);
  hipMemsetAsync(stats, 0, 128 * sizeof(float), stream);

  dim3 cgrid(1024, 4);
  conv0_relu<<<cgrid, 256, 0, stream>>>(image, conv0_w, conv0_b, Y0);
  conv_mfma<0><<<1024, 256, 67584, stream>>>(Y0, Wp,          conv1_b, Y1,
                                             nullptr, nullptr, nullptr);
  conv_mfma<0><<<1024, 256, 67584, stream>>>(Y1, Wp + 102400, conv2_b, Y0,
                                             nullptr, nullptr, nullptr);
  conv_mfma<1><<<1024, 256, 67584, stream>>>(Y0, Wp + 204800, conv3_b, xb,
                                             pos_w, pos_b, stats);
  finalize_stats<<<1, 64, 0, stream>>>(stats, ms);

  fc_mfma<<<4096, 256, 0, stream>>>(xb, ms, wfc, fc1_b, s1f, fc2_b,
                                    ln_in_w, ln_in_b, kb, vT);

  slots_init<<<112, 256, 0, stream>>>(slots_mu, slots_ls, noise, slots);

  for (int it = 0; it < 3; it++) {
    attn_fused<<<1024, 256, 0, stream>>>(slots, ln_sl_w, ln_sl_b, q_w,
                                         kb, vT, Upart, Tpart);
    gru_mlp<<<448, 192, 0, stream>>>(Upart, Tpart, gru_w_ih, gru_w_hh,
                                     gru_b_ih, gru_b_hh, ln_ff_w, ln_ff_b,
                                     mlp1_w, mlp1_b, mlp2_w, mlp2_b, slots);
  }

  hipMemcpyAsync(d_out, slots, 28672 * sizeof(float), hipMemcpyDeviceToDevice, stream);
}